// Round 6
// baseline (102.823 us; speedup 1.0000x reference)
//
#include <hip/hip_runtime.h>
#include <hip/hip_bf16.h>

// QConv1d: x (8,64,16384) f32, w (64,64,9) f32, bias (64) f32
// out (8,64,16384) f32 = conv1d(x, w, pad=4) * 0.125 + bias
// Strategy: cast to bf16 (weights pre-scaled by 0.125 — exact, power of two),
// MFMA f32_16x16x32_bf16, fp32 accumulate, fp32 out.
// Round-11: single-kernel fusion, VGPR-DISCIPLINED (round-8's fusion was
// right structurally — it removed w_rearrange + launch gap — but blew
// past 256 VGPR by holding x-stage regs (96) + wt transients (72) +
// afr (72) at once). Fix:
//   (a) staging = round-0 plain load->convert->write, NO reg-holding;
//   (b) per-wave A-frag build moved AFTER __syncthreads(), fenced with
//       sched_barrier(0) on both sides so wt[18] transients cannot be
//       hoisted into the staging phase or sunk into compute.
// Peak VGPR ~160 (build) / ~125 (compute) -> 2 blocks/CU preserved.
// Compute/store = round-7 layout (16 O per wave, two 128-wide L halves).
#define C_IN    64
#define L_IN    16384
#define O_OUT   64
#define KTAP    9
#define LTILE   256
#define ROWS    272      // LTILE + 16 halo rows (global l in [l0-8, l0+264))
#define RSTRIDE 72       // 64 + 8 pad (multiple of 8 -> 16B-aligned b128 rows)

typedef short          bf16x8 __attribute__((ext_vector_type(8)));   // MFMA A/B frag
typedef unsigned short u16x8  __attribute__((ext_vector_type(8)));
typedef unsigned int   u32x4  __attribute__((ext_vector_type(4)));
typedef float          f32x4  __attribute__((ext_vector_type(4)));   // MFMA C/D frag
typedef float          f32x8v __attribute__((ext_vector_type(8)));

static __device__ __forceinline__ unsigned short f2bf(float f) {
  __hip_bfloat16 h = __float2bfloat16(f);   // round-to-nearest
  return __builtin_bit_cast(unsigned short, h);
}

// pack two floats -> one u32 of two bf16 (lo in low 16 bits)
static __device__ __forceinline__ unsigned int pk2(float lo, float hi) {
  return (unsigned int)f2bf(lo) | ((unsigned int)f2bf(hi) << 16);
}

// ---------------------------------------------------------------------------
// One block = one n, one 256-wide L tile, all 64 outputs. 4 waves, each
// owning 16 O rows; two 128-wide L halves computed sequentially.
// ---------------------------------------------------------------------------
__global__ __launch_bounds__(256) void qconv_kernel(
    const float* __restrict__ x,
    const float* __restrict__ w,
    const float* __restrict__ bias,
    float* __restrict__ out) {

  __shared__ __align__(16) unsigned short xs[ROWS][RSTRIDE];  // bf16 x tile, [l][c]

  const int tid = threadIdx.x;
  const int n   = blockIdx.x >> 6;
  const int l0  = (blockIdx.x & 63) << 8;      // tile base along L
  const float* xn = x + (size_t)n * C_IN * L_IN;

  // ---- Phase 1: stage x tile into LDS (round-0 verbatim: 272 8x8 units,
  //      plain load->pack->write, no reg-holding => VGPR-lean) ------------
  for (int idx = tid; idx < ROWS; idx += 256) {
    const int cb = idx & 7;
    const int lb = idx >> 3;
    const int c0 = cb << 3;
    const int gl0 = l0 - 8 + (lb << 3);        // global l of first row (32B-aligned)
    if (gl0 >= 0 && gl0 + 8 <= L_IN) {
      f32x8v v[8];
#pragma unroll
      for (int i = 0; i < 8; ++i)
        v[i] = *reinterpret_cast<const f32x8v*>(xn + (size_t)(c0 + i) * L_IN + gl0);
#pragma unroll
      for (int j = 0; j < 8; ++j) {
        u32x4 wv;
#pragma unroll
        for (int p = 0; p < 4; ++p)
          wv[p] = pk2(v[2 * p][j], v[2 * p + 1][j]);
        *reinterpret_cast<u32x4*>(&xs[(lb << 3) + j][c0]) = wv;
      }
    } else {
      // edge tiles only: element-wise zero-fill outside [0, L)
      unsigned short vb[8][8];                  // [i=c][j=l]
      for (int i = 0; i < 8; ++i)
        for (int j = 0; j < 8; ++j) {
          int gl = gl0 + j;
          vb[i][j] = (gl >= 0 && gl < L_IN)
                         ? f2bf(xn[(size_t)(c0 + i) * L_IN + gl])
                         : (unsigned short)0;
        }
      for (int j = 0; j < 8; ++j) {
        u16x8 wv;
        for (int i = 0; i < 8; ++i) wv[i] = vb[i][j];
        *reinterpret_cast<u16x8*>(&xs[(lb << 3) + j][c0]) = wv;
      }
    }
  }
  __syncthreads();
  __builtin_amdgcn_sched_barrier(0);   // fence: keep wt transients out of staging

  // ---- Phase 1.5: per-wave A-frag build from global w (L2-resident) -----
  // Lane holds o = wave*16 + col; frag(t,k) = bf16(w[o][k*32+quad*8+i][t]
  // * 0.125), i=0..7, packed c-consecutive (verified correct in round-8).
  const int wave = tid >> 6;
  const int lane = tid & 63;
  const int col  = lane & 15;
  const int quad = lane >> 4;
  const int o16  = (wave << 4) + col;

  u32x4 afr[2 * KTAP];                 // [t*2 + k] — 72 VGPR, live to end
  {
    const float* wrow = w + (size_t)o16 * (C_IN * KTAP);
#pragma unroll
    for (int k = 0; k < 2; ++k) {
      const float* wp = wrow + ((k << 5) + (quad << 3)) * KTAP;  // 72 floats, 16B-aligned
      f32x4 wt[18];
#pragma unroll
      for (int j = 0; j < 18; ++j)
        wt[j] = *reinterpret_cast<const f32x4*>(wp + 4 * j);
#pragma unroll
      for (int t = 0; t < KTAP; ++t) {
        u32x4 fr;
#pragma unroll
        for (int p = 0; p < 4; ++p) {
          const int e0 = (2 * p) * KTAP + t;
          const int e1 = (2 * p + 1) * KTAP + t;
          fr[p] = pk2(wt[e0 >> 2][e0 & 3] * 0.125f,
                      wt[e1 >> 2][e1 & 3] * 0.125f);
        }
        afr[(t << 1) + k] = fr;
      }
    }
  }
  __builtin_amdgcn_sched_barrier(0);   // fence: keep build from sinking into compute

  // ---- Compute ----------------------------------------------------------
  const int obase = (wave << 4) + (quad << 2);
  float bv[4];
#pragma unroll
  for (int reg = 0; reg < 4; ++reg) bv[reg] = bias[obase + reg];

  f32x4 acc[8];
#pragma unroll
  for (int lt = 0; lt < 8; ++lt) acc[lt] = (f32x4){0.f, 0.f, 0.f, 0.f};

  // -- half A: out cols l0 .. l0+127; LDS rows r = col + t + 4 + lt*16 ----
#pragma unroll
  for (int t = 0; t < KTAP; ++t) {
#pragma unroll
    for (int k = 0; k < 2; ++k) {
      const bf16x8 a = __builtin_bit_cast(bf16x8, afr[(t << 1) + k]);
#pragma unroll
      for (int lt = 0; lt < 8; ++lt) {
        const int r = col + t + 4 + (lt << 4);
        const bf16x8 b = *reinterpret_cast<const bf16x8*>(&xs[r][(k << 5) + (quad << 3)]);
        acc[lt] = __builtin_amdgcn_mfma_f32_16x16x32_bf16(a, b, acc[lt], 0, 0, 0);
      }
    }
  }

  // ---- store half A -----------------------------------------------------
#pragma unroll
  for (int lt = 0; lt < 8; ++lt) {
    const int l = l0 + (lt << 4) + col;
#pragma unroll
    for (int reg = 0; reg < 4; ++reg)
      out[((size_t)(n * O_OUT + obase + reg) << 14) + l] = acc[lt][reg] + bv[reg];
  }

  // -- half B: out cols l0+128 .. l0+255; rows r = 128 + col + t + 4 + lt*16
#pragma unroll
  for (int lt = 0; lt < 8; ++lt) acc[lt] = (f32x4){0.f, 0.f, 0.f, 0.f};

#pragma unroll
  for (int t = 0; t < KTAP; ++t) {
#pragma unroll
    for (int k = 0; k < 2; ++k) {
      const bf16x8 a = __builtin_bit_cast(bf16x8, afr[(t << 1) + k]);
#pragma unroll
      for (int lt = 0; lt < 8; ++lt) {
        const int r = 128 + col + t + 4 + (lt << 4);
        const bf16x8 b = *reinterpret_cast<const bf16x8*>(&xs[r][(k << 5) + (quad << 3)]);
        acc[lt] = __builtin_amdgcn_mfma_f32_16x16x32_bf16(a, b, acc[lt], 0, 0, 0);
      }
    }
  }

  // ---- store half B -----------------------------------------------------
#pragma unroll
  for (int lt = 0; lt < 8; ++lt) {
    const int l = l0 + 128 + (lt << 4) + col;
#pragma unroll
    for (int reg = 0; reg < 4; ++reg)
      out[((size_t)(n * O_OUT + obase + reg) << 14) + l] = acc[lt][reg] + bv[reg];
  }
}

extern "C" void kernel_launch(void* const* d_in, const int* in_sizes, int n_in,
                              void* d_out, int out_size, void* d_ws, size_t ws_size,
                              hipStream_t stream) {
  const float* x    = (const float*)d_in[0];
  const float* w    = (const float*)d_in[1];
  const float* bias = (const float*)d_in[2];
  float*       out  = (float*)d_out;
  (void)d_ws; (void)ws_size;

  // single fused dispatch: 8 n * 64 L-tiles = 512 blocks
  qconv_kernel<<<8 * (L_IN / LTILE), 256, 0, stream>>>(x, w, bias, out);
}